// Round 1
// baseline (2841.206 us; speedup 1.0000x reference)
//
#include <hip/hip_runtime.h>

typedef __attribute__((ext_vector_type(8))) short short8;
typedef __attribute__((ext_vector_type(4))) float f32x4;

__device__ __forceinline__ float bf2f(ushort u) {
  union { unsigned int i; float f; } x; x.i = ((unsigned int)u) << 16; return x.f;
}
__device__ __forceinline__ ushort f2bf(float f) {
  union { float f; unsigned int i; } x; x.f = f;
  unsigned int i = x.i + 0x7fffu + ((x.i >> 16) & 1u);
  return (ushort)(i >> 16);
}

// -------- transpose fp32 -> bf16, out[c][r] = bf16(in[r][c]) --------
__global__ void transpose_f2b(const float* __restrict__ in, ushort* __restrict__ out,
                              int R, int C) {
  __shared__ ushort tile[32][33];
  int c0 = blockIdx.x * 32, r0 = blockIdx.y * 32;
  int tx = threadIdx.x, ty = threadIdx.y;  // block (32,8)
  for (int i = 0; i < 32; i += 8) {
    int r = r0 + ty + i, c = c0 + tx;
    if (r < R && c < C) tile[ty + i][tx] = f2bf(in[(size_t)r * C + c]);
  }
  __syncthreads();
  for (int i = 0; i < 32; i += 8) {
    int c = c0 + ty + i, r = r0 + tx;
    if (r < R && c < C) out[(size_t)c * R + r] = tile[tx][ty + i];
  }
}

// -------- gather embedded tokens (fp32 emb -> bf16): embA[t*128+b][:] --------
__global__ void embed_gather(const int* __restrict__ target, const float* __restrict__ emb,
                             ushort* __restrict__ embA) {
  int m = blockIdx.x;            // 0..6015
  int t = m >> 7, b = m & 127;
  int tok = (t == 0) ? 1 : target[b * 48 + t];
  embA[(size_t)m * 256 + threadIdx.x] = f2bf(emb[(size_t)tok * 256 + threadIdx.x]);
}

// ---------------- generic MFMA GEMM: C = act(A[M,K] @ BT[N,K]^T + bias) ----------------
// A: bf16 (or fp32 if flags&8, converted in-register). bias: fp32.
// flags: 1=relu, 2=store fp32, 4=remap rows m=t*128+b -> out row b*47+t, 8=A is fp32
__global__ __launch_bounds__(256) void gemm_bt(
    const void* __restrict__ Ap, const ushort* __restrict__ BT,
    const float* __restrict__ bias, void* __restrict__ Cout,
    int M, int N, int K, int flags) {
  int wave = threadIdx.x >> 6;
  int lane = threadIdx.x & 63;
  int q = lane >> 4, l16 = lane & 15;
  int m0 = blockIdx.y * 64 + (wave & 1) * 32;
  int n0 = blockIdx.x * 64 + (wave >> 1) * 32;
  int koff = q * 8;
  f32x4 acc[2][2];
#pragma unroll
  for (int i = 0; i < 2; ++i)
#pragma unroll
    for (int j = 0; j < 2; ++j) acc[i][j] = (f32x4){0.f, 0.f, 0.f, 0.f};
  for (int k = 0; k < K; k += 32) {
    short8 a[2], b[2];
#pragma unroll
    for (int i = 0; i < 2; ++i) {
      int row = m0 + i * 16 + l16;
      if (flags & 8) {
        const float* src = (const float*)Ap + (size_t)row * K + k + koff;
        short8 t;
#pragma unroll
        for (int e = 0; e < 8; ++e) t[e] = (short)f2bf(src[e]);
        a[i] = t;
      } else {
        a[i] = *(const short8*)((const ushort*)Ap + (size_t)row * K + k + koff);
      }
    }
#pragma unroll
    for (int j = 0; j < 2; ++j) {
      int col = n0 + j * 16 + l16;
      if (col < N) b[j] = *(const short8*)(BT + (size_t)col * K + k + koff);
      else b[j] = (short8){0, 0, 0, 0, 0, 0, 0, 0};
    }
#pragma unroll
    for (int i = 0; i < 2; ++i)
#pragma unroll
      for (int j = 0; j < 2; ++j)
        acc[i][j] = __builtin_amdgcn_mfma_f32_16x16x32_bf16(a[i], b[j], acc[i][j], 0, 0, 0);
  }
#pragma unroll
  for (int i = 0; i < 2; ++i)
#pragma unroll
    for (int j = 0; j < 2; ++j)
#pragma unroll
      for (int r = 0; r < 4; ++r) {
        int gr = m0 + i * 16 + q * 4 + r;   // D row = quad*4 + reg  [m89/m91]
        int gc = n0 + j * 16 + l16;         // D col = lane&15
        if (gc >= N) continue;
        float v = acc[i][j][r];
        if (bias) v += bias[gc];
        if (flags & 1) v = fmaxf(v, 0.f);
        size_t orow = (size_t)gr;
        if (flags & 4) { int t = gr >> 7, bb = gr & 127; orow = (size_t)bb * 47 + t; }
        if (flags & 2) ((float*)Cout)[orow * (size_t)N + gc] = v;
        else ((ushort*)Cout)[orow * (size_t)N + gc] = f2bf(v);
      }
}

// ---------------- fused per-step: hid_w2 matvec + attention ----------------
// One block per batch row b. Replaces the 16-block hidw2 GEMM launch (latency-
// bound, 6% of chip) with a ~1-2us in-block matvec: state[b] is only 512 values.
__global__ __launch_bounds__(256) void attn_step(
    const ushort* __restrict__ state,     // (128,512) bf16, hidden at step t
    const ushort* __restrict__ W2T,       // (512,512) bf16, row u = col u of W2
    const float* __restrict__ b2,         // (512) fp32
    const ushort* __restrict__ featW1,    // (8192, 512) bf16, row = b*64+l
    const ushort* __restrict__ features,  // (8192, 256) bf16
    const float* __restrict__ V,          // (512) fp32
    const float* __restrict__ bV,         // (1)  fp32
    ushort* __restrict__ ctx) {           // (128, 256) bf16
  int b = blockIdx.x, tid = threadIdx.x;
  __shared__ float stf[512], hw2[512], Vv[512], sc[64], attnw[64];
  {
    const ushort* sr = state + (size_t)b * 512;
    stf[tid] = bf2f(sr[tid]);
    stf[tid + 256] = bf2f(sr[tid + 256]);
    Vv[tid] = V[tid];
    Vv[tid + 256] = V[tid + 256];
  }
  __syncthreads();
  // hw2[u] = sum_k state[b][k] * W2[k][u] + b2[u]; W2T row u is contiguous in k.
#pragma unroll 1
  for (int uu = 0; uu < 2; ++uu) {
    int u = tid + uu * 256;
    const short8* w = (const short8*)(W2T + (size_t)u * 512);
    float s = 0.f;
#pragma unroll 4
    for (int k8 = 0; k8 < 64; ++k8) {
      short8 wv = w[k8];
#pragma unroll
      for (int e = 0; e < 8; ++e) s += bf2f((ushort)wv[e]) * stf[k8 * 8 + e];
    }
    hw2[u] = s + b2[u];
  }
  __syncthreads();
  // attention scores: 4 threads per region l, 128 u each
  int l = tid >> 2, part = tid & 3;
  const ushort* fw = featW1 + ((size_t)(b * 64 + l)) * 512 + part * 128;
  float s = 0.f;
  for (int u = 0; u < 128; ++u) {
    float x = bf2f(fw[u]) + hw2[part * 128 + u];
    s += tanhf(x) * Vv[part * 128 + u];
  }
  s += __shfl_xor(s, 1);
  s += __shfl_xor(s, 2);
  if (part == 0) sc[l] = s + bV[0];
  __syncthreads();
  if (tid < 64) {  // softmax over L=64, single wave
    float v = sc[tid], m = v;
    for (int o = 32; o; o >>= 1) m = fmaxf(m, __shfl_xor(m, o));
    float e = __expf(v - m), ssum = e;
    for (int o = 32; o; o >>= 1) ssum += __shfl_xor(ssum, o);
    attnw[tid] = e / ssum;
  }
  __syncthreads();
  float c = 0.f;
  const ushort* fb = features + (size_t)b * 64 * 256 + tid;
  for (int l2 = 0; l2 < 64; ++l2) c += attnw[l2] * bf2f(fb[l2 * 256]);
  ctx[(size_t)b * 256 + tid] = f2bf(c);
}

// ---------------- [ctx | embA_t] @ gru_k (K=512) MFMA + fused GRU gates ----------------
// grid (16 u-tiles of 32, 4 b-tiles of 32); block 256 (waves 0..2 = gates z,r,h)
__global__ __launch_bounds__(256) void gru_gates(
    const ushort* __restrict__ ctx,      // (128,256) bf16
    const ushort* __restrict__ embAt,    // (128,256) bf16 slice for step t
    const ushort* __restrict__ gruT,     // (1536,512) bf16 : row j = col j of gru_k
    const float* __restrict__ grub0,     // gru_b row 0 (1536) fp32
    const float* __restrict__ grub1,     // gru_b row 1 (1536) fp32
    ushort* __restrict__ stateOut) {     // (128,512) bf16
  int wave = threadIdx.x >> 6, lane = threadIdx.x & 63;
  int b0 = blockIdx.y * 32, u0 = blockIdx.x * 32;
  __shared__ float mx[3][32][33];
  if (wave < 3) {
    int n0 = wave * 512 + u0;  // gate wave: z cols, r cols +512, h cols +1024
    int q = lane >> 4, l16 = lane & 15, koff = q * 8;
    f32x4 acc[2][2];
#pragma unroll
    for (int i = 0; i < 2; ++i)
#pragma unroll
      for (int j = 0; j < 2; ++j) acc[i][j] = (f32x4){0.f, 0.f, 0.f, 0.f};
    for (int k = 0; k < 512; k += 32) {
      short8 a[2], bb[2];
#pragma unroll
      for (int i = 0; i < 2; ++i) {
        int row = b0 + i * 16 + l16;
        const ushort* src = (k < 256)
            ? (ctx   + (size_t)row * 256 + k + koff)
            : (embAt + (size_t)row * 256 + (k - 256) + koff);
        a[i] = *(const short8*)src;
      }
#pragma unroll
      for (int j = 0; j < 2; ++j)
        bb[j] = *(const short8*)(gruT + (size_t)(n0 + j * 16 + l16) * 512 + k + koff);
#pragma unroll
      for (int i = 0; i < 2; ++i)
#pragma unroll
        for (int j = 0; j < 2; ++j)
          acc[i][j] = __builtin_amdgcn_mfma_f32_16x16x32_bf16(a[i], bb[j], acc[i][j], 0, 0, 0);
    }
#pragma unroll
    for (int i = 0; i < 2; ++i)
#pragma unroll
      for (int j = 0; j < 2; ++j)
#pragma unroll
        for (int r = 0; r < 4; ++r) {
          int lr = i * 16 + q * 4 + r, lc = j * 16 + l16;
          mx[wave][lr][lc] = acc[i][j][r] + grub0[n0 + lc];
        }
  }
  __syncthreads();
  for (int c = threadIdx.x; c < 1024; c += 256) {
    int bl = c >> 5, ul = c & 31;
    int u = u0 + ul, b = b0 + bl;
    float xz = mx[0][bl][ul] + grub1[u];
    float xr = mx[1][bl][ul] + grub1[512 + u];
    float xh = mx[2][bl][ul];
    float z = 1.f / (1.f + __expf(-xz));
    float r = 1.f / (1.f + __expf(-xr));
    float hh = tanhf(xh + r * grub1[1024 + u]);
    stateOut[(size_t)b * 512 + u] = f2bf((1.f - z) * hh);
  }
}

extern "C" void kernel_launch(void* const* d_in, const int* in_sizes, int n_in,
                              void* d_out, int out_size, void* d_ws, size_t ws_size,
                              hipStream_t stream) {
  const float* img    = (const float*)d_in[0];
  const int*   target = (const int*)d_in[1];
  const float* W_fc   = (const float*)d_in[2];
  const float* b_fc   = (const float*)d_in[3];
  const float* W1     = (const float*)d_in[4];
  const float* b1     = (const float*)d_in[5];
  const float* W2     = (const float*)d_in[6];
  const float* b2     = (const float*)d_in[7];
  const float* V      = (const float*)d_in[8];
  const float* bV     = (const float*)d_in[9];
  const float* emb    = (const float*)d_in[10];
  const float* gru_k  = (const float*)d_in[11];
  /* d_in[12] = gru_rk: dead (h0 == 0 every step) */
  const float* gru_b  = (const float*)d_in[13];
  const float* fc1_w  = (const float*)d_in[14];
  const float* fc1_b  = (const float*)d_in[15];
  const float* fc2_w  = (const float*)d_in[16];
  const float* fc2_b  = (const float*)d_in[17];

  // ---- d_ws layout: transposed bf16 weights + tiny fp32 buffers ----
  char* wsb = (char*)d_ws;
  size_t off = 0;
  auto alloc = [&](size_t bytes) {
    char* p = wsb + off;
    off += (bytes + 255) & ~(size_t)255;
    return p;
  };
  ushort* W_fcT = (ushort*)alloc((size_t)256 * 2048 * 2);   // 1.05 MB
  ushort* W1T   = (ushort*)alloc((size_t)512 * 256 * 2);    // 0.26 MB
  ushort* W2T   = (ushort*)alloc((size_t)512 * 512 * 2);    // 0.52 MB
  ushort* gruT  = (ushort*)alloc((size_t)1536 * 512 * 2);   // 1.57 MB
  ushort* fc1T  = (ushort*)alloc((size_t)512 * 512 * 2);    // 0.52 MB
  ushort* fc2T  = (ushort*)alloc((size_t)5000 * 512 * 2);   // 5.12 MB
  ushort* ctx   = (ushort*)alloc((size_t)128 * 256 * 2);    // 64 KB

  // ---- big bf16 intermediates inside d_out (fp32 out: 120.3 MB; 28.1 MB used).
  // All are dead before the final fc2 GEMM overwrites every element of d_out;
  // fc2 reads only hid2ws which lives in d_ws (no overlap with fc2's writes).
  char* ob = (char*)d_out;
  ushort* features = (ushort*)(ob);                               // 8192x256  = 4.19 MB
  ushort* featW1   = (ushort*)(ob + (size_t)4194304);             // 8192x512  = 8.39 MB
  ushort* states   = (ushort*)(ob + (size_t)12582912);            // 48x128x512= 6.29 MB
  ushort* embA     = (ushort*)(ob + (size_t)18874368);            // 6016x256  = 3.08 MB
  ushort* hid2ws   = (ushort*)alloc((size_t)6016 * 512 * 2);      // 6.16 MB in d_ws

  dim3 tb(32, 8);
  transpose_f2b<<<dim3(8, 64), tb, 0, stream>>>(W_fc, W_fcT, 2048, 256);
  transpose_f2b<<<dim3(16, 8), tb, 0, stream>>>(W1, W1T, 256, 512);
  transpose_f2b<<<dim3(16, 16), tb, 0, stream>>>(W2, W2T, 512, 512);
  transpose_f2b<<<dim3(48, 16), tb, 0, stream>>>(gru_k, gruT, 512, 1536);
  transpose_f2b<<<dim3(16, 16), tb, 0, stream>>>(fc1_w, fc1T, 512, 512);
  transpose_f2b<<<dim3(157, 16), tb, 0, stream>>>(fc2_w, fc2T, 512, 5000);

  embed_gather<<<6016, 256, 0, stream>>>(target, emb, embA);

  // encoder: features = relu(img @ W_fc + b_fc)   (8192,256) K=2048, A fp32 (flag 8)
  gemm_bt<<<dim3(4, 128), 256, 0, stream>>>(img, W_fcT, b_fc, features, 8192, 256, 2048, 1 | 8);
  // featW1 = features @ W1 + b1                   (8192,512) K=256
  gemm_bt<<<dim3(8, 128), 256, 0, stream>>>(features, W1T, b1, featW1, 8192, 512, 256, 0);

  hipMemsetAsync(states, 0, (size_t)128 * 512 * 2, stream);  // hidden_0 = 0

  for (int t = 0; t < 47; ++t) {
    // fused: hid_w2 matvec + attention -> ctx   (one block per batch row)
    attn_step<<<128, 256, 0, stream>>>(states + (size_t)t * 128 * 512, W2T, b2,
                                       featW1, features, V, bV, ctx);
    gru_gates<<<dim3(16, 4), 256, 0, stream>>>(ctx,
                                               embA + (size_t)t * 128 * 256,
                                               gruT, gru_b, gru_b + 1536,
                                               states + (size_t)(t + 1) * 128 * 512);
  }

  // fc1 over all steps: (6016,512) K=512  (reads states in d_out, writes hid2ws in d_ws)
  gemm_bt<<<dim3(8, 94), 256, 0, stream>>>(states + (size_t)128 * 512, fc1T, fc1_b,
                                           hid2ws, 6016, 512, 512, 0);
  // fc2 -> d_out fp32 with (t,b)->(b,t) row remap: (6016,5000) K=512; reads only d_ws,
  // overwrites ALL of d_out (including the bf16 scratch regions above)
  gemm_bt<<<dim3(79, 94), 256, 0, stream>>>(hid2ws, fc2T, fc2_b, d_out, 6016, 5000, 512, 2 | 4);
}